// Round 2
// baseline (9795.367 us; speedup 1.0000x reference)
//
#include <hip/hip_runtime.h>

// Problem constants
#define BB 128   // batch
#define SS 128   // seq len
#define EE 256   // encoder dim
#define DD 256   // LSTM hidden
#define OO 64    // output dim

__device__ __forceinline__ float fsig(float x) {
    return 1.0f / (1.0f + __expf(-x));
}
__device__ __forceinline__ float ftanh(float x) {
    float t = __expf(-2.0f * fabsf(x));
    float r = (1.0f - t) / (1.0f + t);
    return copysignf(r, x);
}

// One block per batch row; the whole 128-step scan is block-local.
// enc_proj lives in REGISTERS: thread t holds er[64] = enc_proj[s=t>>2][(t&3)*64 .. +63]
// (exactly the slice it consumes in the score phase). Workspace use: 256 KB only.
__global__ __launch_bounds__(512) void scan_kernel(
    const float* __restrict__ inp,   // B,S,E
    const float* __restrict__ yhist, // B,S,OO
    const float* __restrict__ h0,    // B,D
    const float* __restrict__ c0,    // B,D
    const float* __restrict__ W1,    // 768 x 256 (Wh|Wc|We stacked rows)
    const float* __restrict__ b1,    // 256
    const float* __restrict__ w2,    // 256
    const float* __restrict__ b2,    // 1
    const float* __restrict__ Wih,   // 64 x 1024
    const float* __restrict__ Whh,   // 256 x 1024
    const float* __restrict__ bih,   // 1024
    const float* __restrict__ bhh,   // 1024
    const float* __restrict__ fcW,   // 320 x 64
    const float* __restrict__ fcb,   // 64
    float* __restrict__ ws_hctx)     // B*512 scratch: [h_T | ctx_T]
{
    __shared__ float sh_h[DD], sh_c[DD], sh_hc[EE], sh_gh[1024];
    __shared__ float sh_alpha[SS];
    __shared__ float sh_ctx[EE], sh_yt[OO], sh_y[OO];
    __shared__ float sh_b1[EE], sh_w2[EE], sh_bs[1024], sh_fcb[OO];
    __shared__ float sh_red[4096];

    const int b = blockIdx.x;
    const int t = threadIdx.x;
    const float* inp_b = inp + b * SS * EE;
    const float b2v = b2[0];
    const int s_own = t >> 2;        // this thread's seq row for scores
    const int e0    = (t & 3) * 64;  // this thread's e-slice base

    if (t < DD) { sh_h[t] = h0[b*DD + t]; sh_c[t] = c0[b*DD + t]; }
    if (t < EE) { sh_b1[t] = b1[t]; sh_w2[t] = w2[t]; }
    if (t < OO) sh_fcb[t] = fcb[t];
    sh_bs[t]       = bih[t]       + bhh[t];
    sh_bs[t + 512] = bih[t + 512] + bhh[t + 512];

    // ---- enc_proj into registers: er[j] = sum_k inp[b,s_own,k] * We[k, e0+j]
    float er[64];
    {
        const float* We = W1 + 512 * EE;
        const float* irow = inp_b + s_own * EE;
        #pragma unroll
        for (int j = 0; j < 64; ++j) er[j] = 0.f;
        #pragma unroll 1
        for (int k = 0; k < EE; ++k) {
            const float xv = irow[k];
            const float* wr = We + k * EE + e0;
            #pragma unroll
            for (int j4 = 0; j4 < 16; ++j4) {
                const float4 w = *(const float4*)(wr + j4 * 4);
                er[j4*4+0] += xv * w.x; er[j4*4+1] += xv * w.y;
                er[j4*4+2] += xv * w.z; er[j4*4+3] += xv * w.w;
            }
        }
    }
    __syncthreads();

    for (int ts = 0; ts < SS; ++ts) {
        if (t < OO) sh_y[t] = yhist[b*SS*OO + ts*OO + t];

        // ---- P1: hc partials -> sh_red[0..2047]  ([kc 0..7][e 0..255])
        {
            const int e4 = (t & 63) * 4, kc = t >> 6;
            float ax = 0.f, ay = 0.f, az = 0.f, aw = 0.f;
            for (int k = kc * 64; k < kc * 64 + 64; ++k) {
                const float xv = (k < DD) ? sh_h[k] : sh_c[k - DD];
                const float4 w = *(const float4*)(W1 + k * EE + e4);
                ax += xv * w.x; ay += xv * w.y; az += xv * w.z; aw += xv * w.w;
            }
            float4 r; r.x = ax; r.y = ay; r.z = az; r.w = aw;
            *(float4*)(&sh_red[kc * 256 + e4]) = r;
        }
        // ---- P1b: gh partials -> sh_red[2048..4095] ([kc 0..1][j 0..1023])
        {
            const int j4 = (t & 255) * 4, kc = t >> 8;
            float ax = 0.f, ay = 0.f, az = 0.f, aw = 0.f;
            for (int k = kc * 128; k < kc * 128 + 128; ++k) {
                const float hv = sh_h[k];
                const float4 w = *(const float4*)(Whh + k * 1024 + j4);
                ax += hv * w.x; ay += hv * w.y; az += hv * w.z; aw += hv * w.w;
            }
            float4 r; r.x = ax; r.y = ay; r.z = az; r.w = aw;
            *(float4*)(&sh_red[2048 + kc * 1024 + j4]) = r;
        }
        __syncthreads();
        if (t < EE) {
            float v = sh_b1[t];
            for (int kc = 0; kc < 8; ++kc) v += sh_red[kc * 256 + t];
            sh_hc[t] = v;
        }
        sh_gh[t]       = sh_red[2048 + t]       + sh_red[3072 + t];
        sh_gh[t + 512] = sh_red[2048 + 512 + t] + sh_red[3072 + 512 + t];
        __syncthreads();

        // ---- P2: score partials from REGISTERS (4 threads per s)
        {
            float acc = 0.f;
            #pragma unroll
            for (int j = 0; j < 64; ++j)
                acc += ftanh(er[j] + sh_hc[e0 + j]) * sh_w2[e0 + j];
            sh_red[t] = acc;   // sh_red[4*s + sub]
        }
        __syncthreads();

        // ---- softmax over S in a single wave (2 scores per lane)
        if (t < 64) {
            const int t1 = t + 64;
            float s0v = sh_red[4*t]  + sh_red[4*t+1]  + sh_red[4*t+2]  + sh_red[4*t+3]  + b2v;
            float s1v = sh_red[4*t1] + sh_red[4*t1+1] + sh_red[4*t1+2] + sh_red[4*t1+3] + b2v;
            float m = fmaxf(s0v, s1v);
            #pragma unroll
            for (int off = 32; off > 0; off >>= 1) m = fmaxf(m, __shfl_xor(m, off));
            float ev0 = __expf(s0v - m), ev1 = __expf(s1v - m);
            float sm = ev0 + ev1;
            #pragma unroll
            for (int off = 32; off > 0; off >>= 1) sm += __shfl_xor(sm, off);
            const float r = 1.0f / sm;
            sh_alpha[t]  = ev0 * r;
            sh_alpha[t1] = ev1 * r;
        }
        __syncthreads();

        // ---- P3: context partials -> sh_red[0..2047] ([sc 0..7][e 0..255])
        {
            const int e4 = (t & 63) * 4, sc = t >> 6;
            float ax = 0.f, ay = 0.f, az = 0.f, aw = 0.f;
            for (int s = sc * 16; s < sc * 16 + 16; ++s) {
                const float a = sh_alpha[s];
                const float4 iv = *(const float4*)(inp_b + s * EE + e4);
                ax += a * iv.x; ay += a * iv.y; az += a * iv.z; aw += a * iv.w;
            }
            float4 r; r.x = ax; r.y = ay; r.z = az; r.w = aw;
            *(float4*)(&sh_red[sc * 256 + e4]) = r;
        }
        __syncthreads();
        if (t < EE) {
            float v = 0.f;
            for (int sc = 0; sc < 8; ++sc) v += sh_red[sc * 256 + t];
            sh_ctx[t] = v;
        }
        __syncthreads();

        // ---- P3b: y_tilde partials (K=320 split into 8 chunks of 40)
        {
            const int k = t & 63, c8 = t >> 6;
            float acc = 0.f;
            for (int kk = c8 * 40; kk < c8 * 40 + 40; ++kk) {
                const float xv = (kk < EE) ? sh_ctx[kk] : sh_y[kk - EE];
                acc += xv * fcW[kk * OO + k];
            }
            sh_red[c8 * 64 + k] = acc;
        }
        __syncthreads();
        if (t < OO) {
            float v = sh_fcb[t];
            for (int c8 = 0; c8 < 8; ++c8) v += sh_red[c8 * 64 + t];
            sh_yt[t] = v;
        }
        __syncthreads();

        // ---- P4: gates partials (Wih, K=64 split in 2)
        {
            const int j4 = (t & 255) * 4, kc = t >> 8;
            float ax = 0.f, ay = 0.f, az = 0.f, aw = 0.f;
            for (int k = kc * 32; k < kc * 32 + 32; ++k) {
                const float yv = sh_yt[k];
                const float4 w = *(const float4*)(Wih + k * 1024 + j4);
                ax += yv * w.x; ay += yv * w.y; az += yv * w.z; aw += yv * w.w;
            }
            float4 r; r.x = ax; r.y = ay; r.z = az; r.w = aw;
            *(float4*)(&sh_red[kc * 1024 + j4]) = r;
        }
        __syncthreads();
        // ---- LSTM pointwise
        if (t < DD) {
            const float gi = sh_red[t]       + sh_red[1024 + t] + sh_gh[t]       + sh_bs[t];
            const float gf = sh_red[256 + t] + sh_red[1280 + t] + sh_gh[256 + t] + sh_bs[256 + t];
            const float gg = sh_red[512 + t] + sh_red[1536 + t] + sh_gh[512 + t] + sh_bs[512 + t];
            const float go = sh_red[768 + t] + sh_red[1792 + t] + sh_gh[768 + t] + sh_bs[768 + t];
            const float cn = fsig(gf) * sh_c[t] + fsig(gi) * ftanh(gg);
            sh_c[t] = cn;
            sh_h[t] = fsig(go) * ftanh(cn);
        }
        __syncthreads();
    }

    // [h_T | context_T] for final GEMM
    ws_hctx[b * 512 + t] = (t < DD) ? sh_h[t] : sh_ctx[t - DD];
}

// out(128 x 8192) = hctx(128 x 512) @ W(512 x 8192) + bias
__global__ __launch_bounds__(256) void out_gemm(
    const float* __restrict__ A,    // 128 x 512
    const float* __restrict__ W,    // 512 x 8192
    const float* __restrict__ bias, // 8192
    float* __restrict__ out)        // 128 x 8192
{
    __shared__ float Ab[128 * 65];  // [m][k] padded
    __shared__ float Bb[64 * 32];   // [k][n]
    const int t = threadIdx.x;
    const int nt = blockIdx.x * 32;
    const int n4 = (t & 7) * 4;
    const int m4 = (t >> 3) * 4;
    float acc[4][4];
    for (int i = 0; i < 4; ++i)
        for (int j = 0; j < 4; ++j) acc[i][j] = 0.f;

    for (int kc = 0; kc < 8; ++kc) {
        for (int i = 0; i < 8; ++i) {
            const int fl = t + i * 256;       // float4 idx 0..2047
            const int m = fl >> 4;
            const int k4 = (fl & 15) * 4;
            const float4 v = *(const float4*)(A + m * 512 + kc * 64 + k4);
            Ab[m * 65 + k4 + 0] = v.x;
            Ab[m * 65 + k4 + 1] = v.y;
            Ab[m * 65 + k4 + 2] = v.z;
            Ab[m * 65 + k4 + 3] = v.w;
        }
        for (int i = 0; i < 2; ++i) {
            const int fl = t + i * 256;       // float4 idx 0..511
            const int k = fl >> 3;
            const int nn4 = (fl & 7) * 4;
            *(float4*)&Bb[k * 32 + nn4] = *(const float4*)(W + (size_t)(kc * 64 + k) * 8192 + nt + nn4);
        }
        __syncthreads();
        for (int k = 0; k < 64; ++k) {
            const float4 bv = *(const float4*)&Bb[k * 32 + n4];
            float av0 = Ab[(m4 + 0) * 65 + k];
            float av1 = Ab[(m4 + 1) * 65 + k];
            float av2 = Ab[(m4 + 2) * 65 + k];
            float av3 = Ab[(m4 + 3) * 65 + k];
            acc[0][0] += av0 * bv.x; acc[0][1] += av0 * bv.y; acc[0][2] += av0 * bv.z; acc[0][3] += av0 * bv.w;
            acc[1][0] += av1 * bv.x; acc[1][1] += av1 * bv.y; acc[1][2] += av1 * bv.z; acc[1][3] += av1 * bv.w;
            acc[2][0] += av2 * bv.x; acc[2][1] += av2 * bv.y; acc[2][2] += av2 * bv.z; acc[2][3] += av2 * bv.w;
            acc[3][0] += av3 * bv.x; acc[3][1] += av3 * bv.y; acc[3][2] += av3 * bv.z; acc[3][3] += av3 * bv.w;
        }
        __syncthreads();
    }
    const float4 bb = *(const float4*)(bias + nt + n4);
    for (int i = 0; i < 4; ++i) {
        float4 r;
        r.x = acc[i][0] + bb.x; r.y = acc[i][1] + bb.y;
        r.z = acc[i][2] + bb.z; r.w = acc[i][3] + bb.w;
        *(float4*)(out + (size_t)(m4 + i) * 8192 + nt + n4) = r;
    }
}

extern "C" void kernel_launch(void* const* d_in, const int* in_sizes, int n_in,
                              void* d_out, int out_size, void* d_ws, size_t ws_size,
                              hipStream_t stream) {
    const float* inp = (const float*)d_in[0];
    const float* yh  = (const float*)d_in[1];
    const float* h0  = (const float*)d_in[2];
    const float* c0  = (const float*)d_in[3];
    const float* W1  = (const float*)d_in[4];
    const float* b1  = (const float*)d_in[5];
    const float* w2  = (const float*)d_in[6];
    const float* b2  = (const float*)d_in[7];
    const float* Wih = (const float*)d_in[8];
    const float* Whh = (const float*)d_in[9];
    const float* bih = (const float*)d_in[10];
    const float* bhh = (const float*)d_in[11];
    const float* fcW = (const float*)d_in[12];
    const float* fcb = (const float*)d_in[13];
    const float* foW = (const float*)d_in[14];
    const float* fob = (const float*)d_in[15];

    float* hctx = (float*)d_ws;   // 128*512 floats = 256 KB only

    scan_kernel<<<dim3(BB), dim3(512), 0, stream>>>(
        inp, yh, h0, c0, W1, b1, w2, b2, Wih, Whh, bih, bhh, fcW, fcb, hctx);
    out_gemm<<<dim3(8192 / 32), dim3(256), 0, stream>>>(hctx, foW, fob, (float*)d_out);
}